// Round 1
// baseline (310.966 us; speedup 1.0000x reference)
//
#include <hip/hip_runtime.h>
#include <math.h>

#define NCONF  64
#define NATOMS 256
#define NCOEFF 45
#define NAOV   12
#define NPAIR  66
#define NZ     8
#define NA     8
#define RAD    384    // 12 * 32
#define ANG    4224   // 66 * 64
#define TOT    4608

// triu_indices(12, k=1), i-major order
__constant__ unsigned char c_iu[NPAIR] = {
    0,0,0,0,0,0,0,0,0,0,0,
    1,1,1,1,1,1,1,1,1,1,
    2,2,2,2,2,2,2,2,2,
    3,3,3,3,3,3,3,3,
    4,4,4,4,4,4,4,
    5,5,5,5,5,5,
    6,6,6,6,6,
    7,7,7,7,
    8,8,8,
    9,9,
    10
};
__constant__ unsigned char c_ju[NPAIR] = {
    1,2,3,4,5,6,7,8,9,10,11,
    2,3,4,5,6,7,8,9,10,11,
    3,4,5,6,7,8,9,10,11,
    4,5,6,7,8,9,10,11,
    5,6,7,8,9,10,11,
    6,7,8,9,10,11,
    7,8,9,10,11,
    8,9,10,11,
    9,10,11,
    10,11,
    11
};

// linspace(0.5, 3.5, 16)  (shfS == shfR: same bounds, same eta=16)
__constant__ float c_shfS[16] = {
    0.5f, 0.7f, 0.9f, 1.1f, 1.3f, 1.5f, 1.7f, 1.9f,
    2.1f, 2.3f, 2.5f, 2.7f, 2.9f, 3.1f, 3.3f, 3.5f
};
// linspace(0.5, 3.5, 8)
__constant__ float c_shfA[8] = {
    0.5f, 0.92857142857f, 1.35714285714f, 1.78571428571f,
    2.21428571429f, 2.64285714286f, 3.07142857143f, 3.5f
};
// cos/sin of shfZ = pi/16 + k*pi/8 (k=0..7); matches linspace(0.19634954, 2.94524311, 8)
__constant__ float c_cosZ[8] = {
     0.98078528f,  0.83146961f,  0.55557023f,  0.19509032f,
    -0.19509032f, -0.55557023f, -0.83146961f, -0.98078528f
};
__constant__ float c_sinZ[8] = {
    0.19509032f, 0.55557023f, 0.83146961f, 0.98078528f,
    0.98078528f, 0.83146961f, 0.55557023f, 0.19509032f
};

// d-block column permutation [0,2,5,4,3,1]: h=0 -> cols {0,2,5}, h=1 -> cols {4,3,1}

__global__ __launch_bounds__(256)
void OrbitalAEVComputer_40492951667225_kernel(const float* __restrict__ coef,
                                              float* __restrict__ out) {
    const int atom = blockIdx.x;
    const float* c = coef + (size_t)atom * NCOEFF;
    float* o = out + (size_t)atom * TOT;
    const int t = threadIdx.x;

    __shared__ float s_dist[NAOV];
    __shared__ float s_nv[NAOV][3];
    __shared__ float s_c95[NPAIR];   // 0.95 * cos_ang  == cos(angle)
    __shared__ float s_sin[NPAIR];   // sqrt(1 - c95^2) == sin(angle) >= 0
    __shared__ float s_avd[NPAIR];
    __shared__ float s_f1[NPAIR * NZ];
    __shared__ float s_f2[NPAIR * NA];

    // ---- phase 1: build the 12 AOV vectors, dist, normalized vectors ----
    if (t < NAOV) {
        float x, y, z;
        if (t < 4) {
            x = c[9 + 3 * t]; y = c[10 + 3 * t]; z = c[11 + 3 * t];
        } else {
            int r = (t - 4) >> 1, h = (t - 4) & 1;
            const int base = 21 + 6 * r;
            if (h == 0) { x = c[base + 0]; y = c[base + 2]; z = c[base + 5]; }
            else        { x = c[base + 4]; y = c[base + 3]; z = c[base + 1]; }
        }
        float d = sqrtf(x * x + y * y + z * z);
        bool zm = (fabsf(x) < 1e-12f) && (fabsf(y) < 1e-12f) && (fabsf(z) < 1e-12f);
        float inv = zm ? 0.0f : 1.0f / d;   // if not masked, d >= 1e-12 -> finite
        s_dist[t] = d;
        s_nv[t][0] = x * inv;
        s_nv[t][1] = y * inv;
        s_nv[t][2] = z * inv;
    }
    __syncthreads();

    // ---- phase 2: per-pair cos/sin/avg-dist (66 threads) ----
    if (t < NPAIR) {
        int i = c_iu[t], j = c_ju[t];
        float cang = s_nv[i][0] * s_nv[j][0]
                   + s_nv[i][1] * s_nv[j][1]
                   + s_nv[i][2] * s_nv[j][2];
        float c95 = 0.95f * cang;
        s_c95[t] = c95;
        s_sin[t] = sqrtf(fmaxf(1.0f - c95 * c95, 0.0f));
        s_avd[t] = 0.5f * (s_dist[i] + s_dist[j]);
    }
    __syncthreads();

    // ---- phase 3: f1[q][z] and f2[q][a] (528 values each) ----
    for (int idx = t; idx < NPAIR * NZ; idx += 256) {
        int q = idx >> 3, k = idx & 7;
        // cos(angle - shfZ) = cos(angle)cos(shfZ) + sin(angle)sin(shfZ)
        float cosa = fmaf(s_c95[q], c_cosZ[k], s_sin[q] * c_sinZ[k]);
        float x = 0.5f * (1.0f + cosa);      // in [0,1]
        x = x * x; x = x * x; x = x * x; x = x * x; x = x * x;  // ^32
        s_f1[idx] = x;
        float dd = s_avd[q] - c_shfA[k];
        s_f2[idx] = __expf(-8.0f * dd * dd);
    }
    __syncthreads();

    // ---- phase 4a: radial, 96 float4 stores (s_aev == r_aev, fold with &15) ----
    if (t < 96) {
        int e = t * 4;            // element 0..383
        int p = e >> 5;           // AOV index
        float d = s_dist[p];
        int k0 = e & 31;          // 4-aligned, never crosses the 16-boundary
        float4 v;
        {
            float df = d - c_shfS[(k0 + 0) & 15]; v.x = __expf(-16.0f * df * df);
        }
        {
            float df = d - c_shfS[(k0 + 1) & 15]; v.y = __expf(-16.0f * df * df);
        }
        {
            float df = d - c_shfS[(k0 + 2) & 15]; v.z = __expf(-16.0f * df * df);
        }
        {
            float df = d - c_shfS[(k0 + 3) & 15]; v.w = __expf(-16.0f * df * df);
        }
        reinterpret_cast<float4*>(o)[t] = v;
    }

    // ---- phase 4b: angular outer-product expansion, 1056 float4 stores ----
    for (int idx4 = t; idx4 < ANG / 4; idx4 += 256) {
        int e = idx4 * 4;         // 0..4223
        int q = e >> 6;
        int z = (e >> 3) & 7;
        int a0 = e & 7;           // 0 or 4
        float f1 = 2.0f * s_f1[q * 8 + z];
        const float* f2 = &s_f2[q * 8 + a0];
        float4 v;
        v.x = f1 * f2[0];
        v.y = f1 * f2[1];
        v.z = f1 * f2[2];
        v.w = f1 * f2[3];
        reinterpret_cast<float4*>(o + RAD)[idx4] = v;
    }
}

extern "C" void kernel_launch(void* const* d_in, const int* in_sizes, int n_in,
                              void* d_out, int out_size, void* d_ws, size_t ws_size,
                              hipStream_t stream) {
    const float* coef = (const float*)d_in[0];
    float* out = (float*)d_out;
    // 64 * 256 = 16384 atoms, one block each
    OrbitalAEVComputer_40492951667225_kernel<<<dim3(NCONF * NATOMS), dim3(256), 0, stream>>>(coef, out);
}